// Round 1
// baseline (132.209 us; speedup 1.0000x reference)
//
#include <hip/hip_runtime.h>
#include <hip/hip_bf16.h>
#include <stdint.h>

// Problem constants (fixed by the reference)
#define B_DIM   128
#define N_DIM   36
#define C_DIM   1024
#define KNB     16
#define NKER    8
#define OUTD    1024
#define BN_NODES (B_DIM * N_DIM)     // 4608
#define E_EDGES  (BN_NODES * KNB)    // 73728
#define PI_F 3.14159265358979323846f

typedef __attribute__((ext_vector_type(8))) short bf16x8;   // 8 bf16 = 4 VGPRs (guide-verified)
typedef __attribute__((ext_vector_type(4))) float floatx4;  // MFMA C/D frag

struct alignas(8) U16x4 { unsigned short x, y, z, w; };

__device__ __forceinline__ unsigned short f2bf(float f) {
  union { float f; uint32_t u; } v; v.f = f;
  uint32_t u = v.u;
  return (unsigned short)((u + 0x7fffu + ((u >> 16) & 1u)) >> 16);  // RNE
}
__device__ __forceinline__ float bf2f(unsigned short h) {
  union { uint32_t u; float f; } v; v.u = ((uint32_t)h) << 16;
  return v.f;
}

// async global -> LDS, 16B per lane (global_load_lds_dwordx4).
// NOTE: HW writes wave-uniform-base + lane*16; our chunk->thread mapping
// matches exactly that pattern (chunk index == wave*64 + lane [+256]).
__device__ __forceinline__ void gload16(const void* g, void* l) {
  __builtin_amdgcn_global_load_lds((__attribute__((address_space(1))) void*)(g),
                                   (__attribute__((address_space(3))) void*)(l),
                                   16, 0, 0);
}

// ---------------------------------------------------------------------------
// Kernel 1: per-edge Gaussian-mixture weights -> edge_w[n][k][j]  (transposed
// layout matching the reference's .transpose(0,2,1))
// ---------------------------------------------------------------------------
__global__ __launch_bounds__(256)
void edge_kernel(const float* __restrict__ centre,   // [BN][2]
                 const int*   __restrict__ nbr,      // [BN][16]
                 const float* __restrict__ gw,       // [E]
                 const float* __restrict__ mrho,     // [8]
                 const float* __restrict__ mth,      // [8]
                 const float* __restrict__ prho,     // [8]
                 const float* __restrict__ pth,      // [8]
                 float* __restrict__ edge_w)         // [BN][8][16]
{
  int e = blockIdx.x * 256 + threadIdx.x;
  if (e >= E_EDGES) return;
  int n = e >> 4;
  int j = e & 15;
  int m = nbr[e];
  float cx = centre[2 * n]     - centre[2 * m];
  float cy = centre[2 * n + 1] - centre[2 * m + 1];
  float rho   = sqrtf(cx * cx + cy * cy);
  float theta = atan2f(cx, cy);          // jnp.arctan2(coord_x, coord_y)

  float w[NKER];
  float sum = 0.f;
#pragma unroll
  for (int k = 0; k < NKER; ++k) {
    float dr = rho - mrho[k];
    float pr = prho[k];
    float wr = expf(-0.5f * dr * dr / (1e-14f + pr * pr));
    float fa = fabsf(theta - mth[k]);
    float sa = fabsf(2.0f * PI_F - fa);
    float mm = fminf(fa, sa);
    float pt = pth[k];
    float wt = expf(-0.5f * mm * mm / (1e-14f + pt * pt));
    float ww = wr * wt;
    w[k] = (ww != ww) ? 0.f : ww;        // NaN guard (reference parity)
    sum += w[k];
  }
  float scale = gw[e] / sum;
#pragma unroll
  for (int k = 0; k < NKER; ++k)
    edge_w[(n * NKER + k) * KNB + j] = w[k] * scale;
}

// ---------------------------------------------------------------------------
// Kernel 2: cast node_feats and conv_w (both fp32) to bf16
// ---------------------------------------------------------------------------
__global__ __launch_bounds__(256)
void cast_kernel(const float* __restrict__ feats,    // [BN*1024]
                 const float* __restrict__ cw,       // [1024*1024]
                 unsigned short* __restrict__ fb,
                 unsigned short* __restrict__ wb)
{
  const int NF4 = (BN_NODES * C_DIM) / 4;   // 1179648
  const int NW4 = (C_DIM * OUTD) / 4;       // 262144
  int tid = blockIdx.x * 256 + threadIdx.x;
  if (tid < NF4) {
    float4 v = ((const float4*)feats)[tid];
    U16x4 o = { f2bf(v.x), f2bf(v.y), f2bf(v.z), f2bf(v.w) };
    ((U16x4*)fb)[tid] = o;
  } else {
    int t = tid - NF4;
    if (t < NW4) {
      float4 v = ((const float4*)cw)[t];
      U16x4 o = { f2bf(v.x), f2bf(v.y), f2bf(v.z), f2bf(v.w) };
      ((U16x4*)wb)[t] = o;
    }
  }
}

// ---------------------------------------------------------------------------
// Kernel 3: proj = feats @ conv_w^T   [4608,1024] x [1024,1024]^T, bf16 MFMA.
// m97 structure: 128x128 tile, BK=32, 4 waves (2x2, 64x64 each), 16x16x32.
// ---------------------------------------------------------------------------
__global__ __launch_bounds__(256)
void gemm_bt(const unsigned short* __restrict__ A,    // [4608][1024] bf16
             const unsigned short* __restrict__ Bt,   // [1024][1024] bf16 (row = out ch, K-major)
             unsigned short* __restrict__ D)          // [4608][1024] bf16
{
  __shared__ unsigned short At [128 * 32];
  __shared__ unsigned short Bts[128 * 32];

  const int tid  = threadIdx.x;
  const int lane = tid & 63;
  const int wave = tid >> 6;
  const int wr   = wave >> 1;       // wave row (0..1) -> 64 rows
  const int wc   = wave & 1;        // wave col (0..1) -> 64 cols
  const int row0 = blockIdx.x * 128;
  const int col0 = blockIdx.y * 128;

  floatx4 acc[4][4] = {};

  // staging: tile = 128 rows x 32 bf16 = 512 x 16B chunks; thread t does
  // chunks t and t+256. chunk c -> row c>>2, 16B-col c&3.
  const int r0 = tid >> 2,         q0 = tid & 3;
  const int r1 = (tid + 256) >> 2; const int q1 = q0;

  const unsigned short* Ag0 = A  + (size_t)(row0 + r0) * C_DIM + q0 * 8;
  const unsigned short* Ag1 = A  + (size_t)(row0 + r1) * C_DIM + q1 * 8;
  const unsigned short* Bg0 = Bt + (size_t)(col0 + r0) * C_DIM + q0 * 8;
  const unsigned short* Bg1 = Bt + (size_t)(col0 + r1) * C_DIM + q1 * 8;
  unsigned short* la0 = &At [tid * 8];
  unsigned short* la1 = &At [(tid + 256) * 8];
  unsigned short* lb0 = &Bts[tid * 8];
  unsigned short* lb1 = &Bts[(tid + 256) * 8];

  const int qk = (lane >> 4) << 3;   // k-offset within BK=32 (quad*8)
  const int lr = lane & 15;          // fragment row/col within 16

  for (int k0 = 0; k0 < C_DIM; k0 += 32) {
    gload16(Ag0 + k0, la0);
    gload16(Ag1 + k0, la1);
    gload16(Bg0 + k0, lb0);
    gload16(Bg1 + k0, lb1);
    __syncthreads();   // compiler drains vmcnt before s_barrier

    bf16x8 af[4], bfr[4];
#pragma unroll
    for (int i = 0; i < 4; ++i) {
      af[i]  = *(const bf16x8*)&At [(wr * 64 + i * 16 + lr) * 32 + qk];
      bfr[i] = *(const bf16x8*)&Bts[(wc * 64 + i * 16 + lr) * 32 + qk];
    }
#pragma unroll
    for (int i = 0; i < 4; ++i)
#pragma unroll
      for (int j = 0; j < 4; ++j)
        acc[i][j] = __builtin_amdgcn_mfma_f32_16x16x32_bf16(af[i], bfr[j], acc[i][j], 0, 0, 0);
    __syncthreads();
  }

  // epilogue: C/D layout col=lane&15, row=(lane>>4)*4+reg (m89-verified)
  const int quad = lane >> 4;
#pragma unroll
  for (int i = 0; i < 4; ++i)
#pragma unroll
    for (int j = 0; j < 4; ++j)
#pragma unroll
      for (int r = 0; r < 4; ++r) {
        int row = row0 + wr * 64 + i * 16 + quad * 4 + r;
        int col = col0 + wc * 64 + j * 16 + lr;
        D[(size_t)row * OUTD + col] = f2bf(acc[i][j][r]);
      }
}

// ---------------------------------------------------------------------------
// Kernel 4: out[n][c] = relu( sum_j edge_w[n][c/128][j] * proj[idx[n][j]][c] )
// one block per node; thread t handles channels 4t..4t+3 (k = t/32)
// ---------------------------------------------------------------------------
__global__ __launch_bounds__(256)
void agg_kernel(const unsigned short* __restrict__ proj,  // [BN][1024] bf16
                const float* __restrict__ edge_w,         // [BN][8][16]
                const int*   __restrict__ nbr,            // [BN][16]
                float* __restrict__ out)                  // [BN][1024] fp32
{
  __shared__ float ew[NKER * KNB];   // 128
  __shared__ int   idx[KNB];
  const int n = blockIdx.x;
  const int t = threadIdx.x;
  if (t < 128)            ew[t]        = edge_w[n * 128 + t];
  else if (t < 128 + KNB) idx[t - 128] = nbr[n * KNB + (t - 128)];
  __syncthreads();

  const int k = t >> 5;   // (4t)/128
  float a0 = 0.f, a1 = 0.f, a2 = 0.f, a3 = 0.f;
#pragma unroll
  for (int j = 0; j < KNB; ++j) {
    float wv = ew[k * KNB + j];      // LDS broadcast within 32-thread group
    U16x4 v = *(const U16x4*)&proj[(size_t)idx[j] * OUTD + t * 4];
    a0 += wv * bf2f(v.x);
    a1 += wv * bf2f(v.y);
    a2 += wv * bf2f(v.z);
    a3 += wv * bf2f(v.w);
  }
  float4 r;
  r.x = fmaxf(a0, 0.f); r.y = fmaxf(a1, 0.f);
  r.z = fmaxf(a2, 0.f); r.w = fmaxf(a3, 0.f);
  ((float4*)out)[(size_t)n * (OUTD / 4) + t] = r;
}

// ---------------------------------------------------------------------------
extern "C" void kernel_launch(void* const* d_in, const int* in_sizes, int n_in,
                              void* d_out, int out_size, void* d_ws, size_t ws_size,
                              hipStream_t stream)
{
  const float* feats  = (const float*)d_in[0];   // [128,36,1024]
  const float* centre = (const float*)d_in[1];   // [128,36,2]
  const int*   nbr    = (const int*)  d_in[2];   // [4608,16]
  const float* gw     = (const float*)d_in[3];   // [73728,1]
  const float* mrho   = (const float*)d_in[4];
  const float* mth    = (const float*)d_in[5];
  const float* prho   = (const float*)d_in[6];
  const float* pth    = (const float*)d_in[7];
  const float* cw     = (const float*)d_in[8];   // [8,128,1024] == [1024,1024]
  float* out = (float*)d_out;

  // workspace layout (total ~23.3 MB)
  char* ws = (char*)d_ws;
  unsigned short* fb    = (unsigned short*)(ws);              //  9,437,184 B
  unsigned short* wb    = (unsigned short*)(ws + 9437184);    //  2,097,152 B
  unsigned short* proj  = (unsigned short*)(ws + 11534336);   //  9,437,184 B
  float*          edgew = (float*)         (ws + 20971520);   //  2,359,296 B

  edge_kernel<<<dim3(E_EDGES / 256), dim3(256), 0, stream>>>(
      centre, nbr, gw, mrho, mth, prho, pth, edgew);
  cast_kernel<<<dim3(((BN_NODES * C_DIM) / 4 + (C_DIM * OUTD) / 4) / 256), dim3(256), 0, stream>>>(
      feats, cw, fb, wb);
  gemm_bt<<<dim3(BN_NODES / 128, OUTD / 128), dim3(256), 0, stream>>>(fb, wb, proj);
  agg_kernel<<<dim3(BN_NODES), dim3(256), 0, stream>>>(proj, edgew, nbr, out);
}

// Round 2
// 128.004 us; speedup vs baseline: 1.0328x; 1.0328x over previous
//
#include <hip/hip_runtime.h>
#include <hip/hip_bf16.h>
#include <stdint.h>

// Problem constants (fixed by the reference)
#define B_DIM   128
#define N_DIM   36
#define C_DIM   1024
#define KNB     16
#define NKER    8
#define OUTD    1024
#define BN_NODES (B_DIM * N_DIM)     // 4608
#define E_EDGES  (BN_NODES * KNB)    // 73728
#define PI_F 3.14159265358979323846f

typedef __attribute__((ext_vector_type(8))) short bf16x8;   // 8 bf16 = 4 VGPRs
typedef __attribute__((ext_vector_type(4))) float floatx4;  // MFMA C/D frag

struct alignas(8) U16x4 { unsigned short x, y, z, w; };

__device__ __forceinline__ unsigned short f2bf(float f) {
  union { float f; uint32_t u; } v; v.f = f;
  uint32_t u = v.u;
  return (unsigned short)((u + 0x7fffu + ((u >> 16) & 1u)) >> 16);  // RNE
}
__device__ __forceinline__ float bf2f(unsigned short h) {
  union { uint32_t u; float f; } v; v.u = ((uint32_t)h) << 16;
  return v.f;
}

// async global -> LDS, 16B per lane (global_load_lds_dwordx4).
__device__ __forceinline__ void gload16(const void* g, void* l) {
  __builtin_amdgcn_global_load_lds((__attribute__((address_space(1))) void*)(g),
                                   (__attribute__((address_space(3))) void*)(l),
                                   16, 0, 0);
}

// Raw waitcnt/barrier for the software-pipelined K-loop (AITER-style:
// fine-grained vmcnt that is NEVER 0 in steady state, so prefetch loads
// stay in flight across the barrier).
#define VMCNT(n) asm volatile("s_waitcnt vmcnt(" #n ")" ::: "memory")
#define LGKM0()  asm volatile("s_waitcnt lgkmcnt(0)" ::: "memory")

// ---------------------------------------------------------------------------
// Kernel 1: cast node_feats and conv_w (both fp32) to bf16
// ---------------------------------------------------------------------------
__global__ __launch_bounds__(256)
void cast_kernel(const float* __restrict__ feats,    // [BN*1024]
                 const float* __restrict__ cw,       // [1024*1024]
                 unsigned short* __restrict__ fb,
                 unsigned short* __restrict__ wb)
{
  const int NF4 = (BN_NODES * C_DIM) / 4;   // 1179648
  const int NW4 = (C_DIM * OUTD) / 4;       // 262144
  int tid = blockIdx.x * 256 + threadIdx.x;
  if (tid < NF4) {
    float4 v = ((const float4*)feats)[tid];
    U16x4 o = { f2bf(v.x), f2bf(v.y), f2bf(v.z), f2bf(v.w) };
    ((U16x4*)fb)[tid] = o;
  } else {
    int t = tid - NF4;
    if (t < NW4) {
      float4 v = ((const float4*)cw)[t];
      U16x4 o = { f2bf(v.x), f2bf(v.y), f2bf(v.z), f2bf(v.w) };
      ((U16x4*)wb)[t] = o;
    }
  }
}

// ---------------------------------------------------------------------------
// Kernel 2: proj = feats @ conv_w^T   [4608,1024] x [1024,1024]^T, bf16 MFMA.
// 128x128 tile, BK=32, 4 waves (2x2 of 64x64), 16x16x32 MFMA.
// Depth-4 LDS pipeline with raw s_barrier + vmcnt(12): only 288 blocks
// (1.1/CU) exist, so there is no inter-block overlap — latency must be
// hidden INSIDE the block (3 tiles always in flight).
// ---------------------------------------------------------------------------
__global__ __launch_bounds__(256)
void gemm_bt(const unsigned short* __restrict__ A,    // [4608][1024] bf16
             const unsigned short* __restrict__ Bt,   // [1024][1024] bf16
             unsigned short* __restrict__ D)          // [4608][1024] bf16
{
  __shared__ unsigned short At [4][128 * 32];   // 4 x 8 KB
  __shared__ unsigned short Bts[4][128 * 32];   // 4 x 8 KB   (total 64 KB)

  const int tid  = threadIdx.x;
  const int lane = tid & 63;
  const int wave = tid >> 6;
  const int wr   = wave >> 1;       // wave row (0..1) -> 64 rows
  const int wc   = wave & 1;        // wave col (0..1) -> 64 cols
  const int row0 = blockIdx.x * 128;
  const int col0 = blockIdx.y * 128;

  floatx4 acc[4][4] = {};

  // staging: tile = 128 rows x 32 bf16 = 512 x 16B chunks; thread t does
  // chunks t and t+256. chunk c -> row c>>2, 16B-col c&3.
  const int r0 = tid >> 2, q = tid & 3;
  const int r1 = r0 + 64;

  const unsigned short* Ag0 = A  + (size_t)(row0 + r0) * C_DIM + q * 8;
  const unsigned short* Ag1 = A  + (size_t)(row0 + r1) * C_DIM + q * 8;
  const unsigned short* Bg0 = Bt + (size_t)(col0 + r0) * C_DIM + q * 8;
  const unsigned short* Bg1 = Bt + (size_t)(col0 + r1) * C_DIM + q * 8;

  const int qk = (lane >> 4) << 3;   // k-offset within BK=32 (quad*8)
  const int lr = lane & 15;          // fragment row/col within 16

#define STAGE(s, k0) do {                              \
    gload16(Ag0 + (k0), &At [s][tid * 8]);             \
    gload16(Ag1 + (k0), &At [s][(tid + 256) * 8]);     \
    gload16(Bg0 + (k0), &Bts[s][tid * 8]);             \
    gload16(Bg1 + (k0), &Bts[s][(tid + 256) * 8]);     \
  } while (0)

#define FRAGS(s)                                                           \
    bf16x8 af[4], bfr[4];                                                  \
    _Pragma("unroll") for (int i = 0; i < 4; ++i) {                        \
      af[i]  = *(const bf16x8*)&At [s][(wr * 64 + i * 16 + lr) * 32 + qk]; \
      bfr[i] = *(const bf16x8*)&Bts[s][(wc * 64 + i * 16 + lr) * 32 + qk]; \
    }

#define MFMAS()                                                            \
    _Pragma("unroll") for (int i = 0; i < 4; ++i)                          \
    _Pragma("unroll") for (int j = 0; j < 4; ++j)                          \
      acc[i][j] = __builtin_amdgcn_mfma_f32_16x16x32_bf16(af[i], bfr[j], acc[i][j], 0, 0, 0);

  // prologue: fill the 4-stage ring
  STAGE(0, 0); STAGE(1, 32); STAGE(2, 64); STAGE(3, 96);

  // steady state: 28 iterations, always 3 tiles (12 loads) in flight
#pragma unroll 4
  for (int it = 0; it < 28; ++it) {
    const int s = it & 3;
    VMCNT(12);                       // tile `it` landed (per-wave)
    __builtin_amdgcn_s_barrier();    // ...for ALL waves
    FRAGS(s);
    LGKM0();                         // frags in regs -> buf s reusable
    __builtin_amdgcn_s_barrier();    // all waves done reading buf s
    STAGE(s, (it + 4) * 32);         // prefetch tile it+4 into buf s
    MFMAS();
  }
  // tail: drain remaining 4 tiles (no more staging -> no WAR barrier)
  { VMCNT(12); __builtin_amdgcn_s_barrier(); FRAGS(0); MFMAS(); }
  { VMCNT(8);  __builtin_amdgcn_s_barrier(); FRAGS(1); MFMAS(); }
  { VMCNT(4);  __builtin_amdgcn_s_barrier(); FRAGS(2); MFMAS(); }
  { VMCNT(0);  __builtin_amdgcn_s_barrier(); FRAGS(3); MFMAS(); }

  // epilogue: C/D layout col=lane&15, row=(lane>>4)*4+reg (m89-verified)
  const int quad = lane >> 4;
#pragma unroll
  for (int i = 0; i < 4; ++i)
#pragma unroll
    for (int j = 0; j < 4; ++j)
#pragma unroll
      for (int r = 0; r < 4; ++r) {
        int row = row0 + wr * 64 + i * 16 + quad * 4 + r;
        int col = col0 + wc * 64 + j * 16 + lr;
        D[(size_t)row * OUTD + col] = f2bf(acc[i][j][r]);
      }
#undef STAGE
#undef FRAGS
#undef MFMAS
}

// ---------------------------------------------------------------------------
// Kernel 3: fused edge-weight + aggregate.
// Block n: prologue computes the 8x16 Gaussian-mixture edge weights for
// node n's 16 edges (was a separate kernel), then
// out[n][c] = relu( sum_j ew[c/128][j] * proj[idx[n][j]][c] )
// ---------------------------------------------------------------------------
__global__ __launch_bounds__(256)
void agg_fused(const unsigned short* __restrict__ proj,  // [BN][1024] bf16
               const float* __restrict__ centre,         // [BN][2]
               const int*   __restrict__ nbr,            // [BN][16]
               const float* __restrict__ gw,             // [E]
               const float* __restrict__ mrho,
               const float* __restrict__ mth,
               const float* __restrict__ prho,
               const float* __restrict__ pth,
               float* __restrict__ out)                  // [BN][1024] fp32
{
  __shared__ int   idx[KNB];
  __shared__ float nx[KNB], ny[KNB];
  __shared__ float cc[2];
  __shared__ float wk[KNB][NKER];
  __shared__ float scl[KNB];
  __shared__ float ew[NKER][KNB];

  const int n = blockIdx.x;
  const int t = threadIdx.x;

  if (t < KNB) {
    int m = nbr[n * KNB + t];
    idx[t] = m;
    nx[t] = centre[2 * m];
    ny[t] = centre[2 * m + 1];
  } else if (t == KNB) {
    cc[0] = centre[2 * n];
    cc[1] = centre[2 * n + 1];
  }
  __syncthreads();

  if (t < 128) {                       // edge j = t>>3, kernel k = t&7
    int j = t >> 3, k = t & 7;
    float cx = cc[0] - nx[j];
    float cy = cc[1] - ny[j];
    float rho   = sqrtf(cx * cx + cy * cy);
    float theta = atan2f(cx, cy);      // jnp.arctan2(coord_x, coord_y)
    float dr = rho - mrho[k];
    float pr = prho[k];
    float w_r = expf(-0.5f * dr * dr / (1e-14f + pr * pr));
    float fa = fabsf(theta - mth[k]);
    float sa = fabsf(2.0f * PI_F - fa);
    float mm = fminf(fa, sa);
    float pt = pth[k];
    float w_t = expf(-0.5f * mm * mm / (1e-14f + pt * pt));
    float ww = w_r * w_t;
    wk[j][k] = (ww != ww) ? 0.f : ww;  // NaN guard (reference parity)
  }
  __syncthreads();

  if (t < KNB) {
    float s = 0.f;
#pragma unroll
    for (int k = 0; k < NKER; ++k) s += wk[t][k];
    scl[t] = gw[n * KNB + t] / s;
  }
  __syncthreads();

  if (t < 128) {
    int j = t >> 3, k = t & 7;
    ew[k][j] = wk[j][k] * scl[j];
  }
  __syncthreads();

  // main aggregate: thread t handles channels 4t..4t+3, k = t/32
  const int k = t >> 5;
  float a0 = 0.f, a1 = 0.f, a2 = 0.f, a3 = 0.f;
#pragma unroll
  for (int j = 0; j < KNB; ++j) {
    float wv = ew[k][j];               // LDS broadcast within 32-thread group
    U16x4 v = *(const U16x4*)&proj[(size_t)idx[j] * OUTD + t * 4];
    a0 += wv * bf2f(v.x);
    a1 += wv * bf2f(v.y);
    a2 += wv * bf2f(v.z);
    a3 += wv * bf2f(v.w);
  }
  float4 r;
  r.x = fmaxf(a0, 0.f); r.y = fmaxf(a1, 0.f);
  r.z = fmaxf(a2, 0.f); r.w = fmaxf(a3, 0.f);
  ((float4*)out)[(size_t)n * (OUTD / 4) + t] = r;
}

// ---------------------------------------------------------------------------
extern "C" void kernel_launch(void* const* d_in, const int* in_sizes, int n_in,
                              void* d_out, int out_size, void* d_ws, size_t ws_size,
                              hipStream_t stream)
{
  const float* feats  = (const float*)d_in[0];   // [128,36,1024]
  const float* centre = (const float*)d_in[1];   // [128,36,2]
  const int*   nbr    = (const int*)  d_in[2];   // [4608,16]
  const float* gw     = (const float*)d_in[3];   // [73728,1]
  const float* mrho   = (const float*)d_in[4];
  const float* mth    = (const float*)d_in[5];
  const float* prho   = (const float*)d_in[6];
  const float* pth    = (const float*)d_in[7];
  const float* cw     = (const float*)d_in[8];   // [8,128,1024] == [1024,1024]
  float* out = (float*)d_out;

  // workspace layout (total 20 MB)
  char* ws = (char*)d_ws;
  unsigned short* fb   = (unsigned short*)(ws);              //  9,437,184 B
  unsigned short* wb   = (unsigned short*)(ws + 9437184);    //  2,097,152 B
  unsigned short* proj = (unsigned short*)(ws + 11534336);   //  9,437,184 B

  cast_kernel<<<dim3(((BN_NODES * C_DIM) / 4 + (C_DIM * OUTD) / 4) / 256),
                dim3(256), 0, stream>>>(feats, cw, fb, wb);
  gemm_bt<<<dim3(BN_NODES / 128, OUTD / 128), dim3(256), 0, stream>>>(fb, wb, proj);
  agg_fused<<<dim3(BN_NODES), dim3(256), 0, stream>>>(
      proj, centre, nbr, gw, mrho, mth, prho, pth, out);
}